// Round 4
// baseline (346.169 us; speedup 1.0000x reference)
//
#include <hip/hip_runtime.h>
#include <math.h>

// Circular 3D cross-correlation via FFT, B=8, V=128.
// Z = v1 + i*v2 packed complex FFT; Hermitian split; G = F1*conj(F2); inverse.
// Storage: each transformed axis in bit-reversed order; pairs k<->-k via
// bitrev7 per axis (same convention as all passing rounds).
//
// Round-7 mechanics:
//  * Same structure as round-6 (K1/K3: 512 thr, half-plane LDS, register
//    retention; K2: quarter-slice pairs). ONE change: amdgpu_waves_per_eu(4,4)
//    on every kernel. Round-6 counters showed VGPR_Count pinned at 64 (the
//    8-waves/SIMD boundary) while liveness is ~100 -> ~40 regs/thread spilled
//    to scratch (WRITE_SIZE 186 MB vs 134 MB actual). LDS already caps
//    occupancy at 4 waves/SIMD, so the allocator was spilling for occupancy
//    it can never get. Pinning (4,4) unlocks the 128-VGPR budget.
//  * FFT core (WF16) unchanged: 16 elem/lane, DPP-only cross-lane stages.

#define V    128
#define V2   16384
#define V3   2097152
#define NB   8
#define P1   68             // K1 LDS pitch (float2): [128 rows][64 x], 2P%32==8
#define P3   132            // K3 LDS pitch (float2): [64 y][128 x],  2P%32==8
#define PH3  34             // K2 LDS pitch (float2) for 32-wide slices
#define SLICE (V * PH3)     // 4352 float2 = 34816 B

#define WPEU4 __attribute__((amdgpu_waves_per_eu(4, 4)))

__device__ __forceinline__ int bitrev7(int x) {
  return (int)(__brev((unsigned)x) >> 25);
}
__device__ __forceinline__ int negrev(int j) {
  int k = bitrev7(j);
  return bitrev7((V - k) & (V - 1));
}

__device__ __forceinline__ float2 cmul(float2 a, float2 b) {
  return make_float2(a.x * b.x - a.y * b.y, a.x * b.y + a.y * b.x);
}
__device__ __forceinline__ float2 cmulc(float2 a, float2 b) {  // a * conj(b)
  return make_float2(a.x * b.x + a.y * b.y, a.y * b.x - a.x * b.y);
}
__device__ __forceinline__ float2 csqr(float2 a) {
  return make_float2(a.x * a.x - a.y * a.y, 2.0f * a.x * a.y);
}
__device__ __forceinline__ float2 f2add(float2 a, float2 b) {
  return make_float2(a.x + b.x, a.y + b.y);
}
__device__ __forceinline__ float2 f2sub(float2 a, float2 b) {
  return make_float2(a.x - b.x, a.y - b.y);
}
__device__ __forceinline__ float2 NI(float2 z) { return make_float2(z.y, -z.x); }  // z*(-i)
__device__ __forceinline__ float2 PI(float2 z) { return make_float2(-z.y, z.x); }  // z*(+i)

// DPP lane exchange: 0xB1 = quad_perm[1,0,3,2] (lane^1),
// 0x4E = quad_perm[2,3,0,1] (lane^2), 0x141 = row_half_mirror (lane^7).
template <int CTRL>
__device__ __forceinline__ float dppf(float v) {
  return __int_as_float(
      __builtin_amdgcn_update_dpp(0, __float_as_int(v), CTRL, 0xF, 0xF, true));
}
template <int CTRL>
__device__ __forceinline__ float2 dpp2(float2 v) {
  return make_float2(dppf<CTRL>(v.x), dppf<CTRL>(v.y));
}

// 128-pt radix-2 FFT: lane lq (0..7 in group) holds elements n = e + 8j,
// j=0..15, e = lq ^ 3*bit2(lq). Fwd DIF h=64..8 in-lane, h=4,2,1 via DPP.
// Inv DIT mirrored with conjugated twiddles (cmulc on the same table).
struct WF16 {
  float2 T64[4], T32[2], T16a, T16b, T8w, ts4, ts2;
  float sg4, sg2, sg1;
  bool up4, up2;
  int e;

  __device__ void init(int lq) {
    e = lq ^ (((lq >> 2) & 1) * 3);
    const float k = -6.28318530717958647692f / 128.0f;
    float2 w1 = make_float2(cosf(k * (float)e), sinf(k * (float)e));  // W128^e
    const float C1 = 0.92387953251128675613f;   // cos(pi/8)
    const float S1 = 0.38268343236508977173f;   // sin(pi/8)
    const float R  = 0.70710678118654752440f;
    T64[0] = w1;                                  // W128^{e+8j} = w1*W16^j
    T64[1] = cmul(w1, make_float2(C1, -S1));
    T64[2] = cmul(w1, make_float2(R, -R));
    T64[3] = cmul(w1, make_float2(S1, -C1));      // j>=4 derived via *(-i)
    float2 w2 = csqr(w1);                         // W128^{2e}
    T32[0] = w2;
    T32[1] = cmul(w2, make_float2(R, -R));        // j0>=2 derived via *(-i)
    T16a = csqr(w2);                              // W128^{4e}
    T16b = NI(T16a);                              // W128^{4e+32}
    T8w = csqr(T16a);                             // W128^{8e}
    up4 = (e >> 2) & 1;
    up2 = (e >> 1) & 1;
    const bool up1 = e & 1;
    sg4 = up4 ? -1.0f : 1.0f;
    sg2 = up2 ? -1.0f : 1.0f;
    sg1 = up1 ? -1.0f : 1.0f;
    const int m4 = e & 3;
    float2 w8p = (m4 == 0) ? make_float2(1.0f, 0.0f)
               : (m4 == 1) ? make_float2(R, -R)
               : (m4 == 2) ? make_float2(0.0f, -1.0f)
                           : make_float2(-R, -R);
    ts4 = up4 ? w8p : make_float2(1.0f, 0.0f);    // W8^{e&3} on upper half
    ts2 = (up2 && (e & 1)) ? make_float2(0.0f, -1.0f) : make_float2(1.0f, 0.0f);
  }

  __device__ __forceinline__ void fwd(float2 c[16]) const {
#pragma unroll
    for (int j = 0; j < 8; ++j) {                 // h=64
      float2 u = c[j], v = c[j + 8];
      c[j] = f2add(u, v);
      float2 t = cmul(f2sub(u, v), T64[j & 3]);
      c[j + 8] = (j < 4) ? t : NI(t);
    }
#pragma unroll
    for (int g = 0; g < 2; ++g) {                 // h=32
#pragma unroll
      for (int j0 = 0; j0 < 4; ++j0) {
        const int j = g * 8 + j0;
        float2 u = c[j], v = c[j + 4];
        c[j] = f2add(u, v);
        float2 t = cmul(f2sub(u, v), T32[j0 & 1]);
        c[j + 4] = (j0 < 2) ? t : NI(t);
      }
    }
#pragma unroll
    for (int g = 0; g < 4; ++g) {                 // h=16
#pragma unroll
      for (int j0 = 0; j0 < 2; ++j0) {
        const int j = g * 4 + j0;
        float2 u = c[j], v = c[j + 2];
        c[j] = f2add(u, v);
        c[j + 2] = cmul(f2sub(u, v), j0 ? T16b : T16a);
      }
    }
#pragma unroll
    for (int j = 0; j < 16; j += 2) {             // h=8
      float2 u = c[j], v = c[j + 1];
      c[j] = f2add(u, v);
      c[j + 1] = cmul(f2sub(u, v), T8w);
    }
#pragma unroll
    for (int j = 0; j < 16; ++j) {                // h=4 : lane^7
      float2 p = dpp2<0x141>(c[j]);
      float2 t = make_float2(fmaf(c[j].x, sg4, p.x), fmaf(c[j].y, sg4, p.y));
      c[j] = cmul(t, ts4);
    }
#pragma unroll
    for (int j = 0; j < 16; ++j) {                // h=2 : lane^2
      float2 p = dpp2<0x4E>(c[j]);
      float2 t = make_float2(fmaf(c[j].x, sg2, p.x), fmaf(c[j].y, sg2, p.y));
      c[j] = cmul(t, ts2);
    }
#pragma unroll
    for (int j = 0; j < 16; ++j) {                // h=1 : lane^1 (tw = 1)
      float2 p = dpp2<0xB1>(c[j]);
      c[j] = make_float2(fmaf(c[j].x, sg1, p.x), fmaf(c[j].y, sg1, p.y));
    }
  }

  __device__ __forceinline__ void inv(float2 c[16]) const {
#pragma unroll
    for (int j = 0; j < 16; ++j) {                // h=1
      float2 p = dpp2<0xB1>(c[j]);
      c[j] = make_float2(fmaf(c[j].x, sg1, p.x), fmaf(c[j].y, sg1, p.y));
    }
#pragma unroll
    for (int j = 0; j < 16; ++j) {                // h=2
      float2 m = cmulc(c[j], ts2);
      float2 q = make_float2(up2 ? m.x : c[j].x, up2 ? m.y : c[j].y);
      float2 p = dpp2<0x4E>(q);
      c[j] = make_float2(fmaf(q.x, sg2, p.x), fmaf(q.y, sg2, p.y));
    }
#pragma unroll
    for (int j = 0; j < 16; ++j) {                // h=4
      float2 m = cmulc(c[j], ts4);
      float2 q = make_float2(up4 ? m.x : c[j].x, up4 ? m.y : c[j].y);
      float2 p = dpp2<0x141>(q);
      c[j] = make_float2(fmaf(q.x, sg4, p.x), fmaf(q.y, sg4, p.y));
    }
#pragma unroll
    for (int j = 0; j < 16; j += 2) {             // h=8
      float2 m = cmulc(c[j + 1], T8w);
      float2 u = c[j];
      c[j] = f2add(u, m);
      c[j + 1] = f2sub(u, m);
    }
#pragma unroll
    for (int g = 0; g < 4; ++g) {                 // h=16
#pragma unroll
      for (int j0 = 0; j0 < 2; ++j0) {
        const int j = g * 4 + j0;
        float2 m = cmulc(c[j + 2], j0 ? T16b : T16a);
        float2 u = c[j];
        c[j] = f2add(u, m);
        c[j + 2] = f2sub(u, m);
      }
    }
#pragma unroll
    for (int g = 0; g < 2; ++g) {                 // h=32
#pragma unroll
      for (int j0 = 0; j0 < 4; ++j0) {
        const int j = g * 8 + j0;
        float2 m0 = cmulc(c[j + 4], T32[j0 & 1]);
        float2 m = (j0 < 2) ? m0 : PI(m0);        // conj(T*(-i)) = conj(T)*i
        float2 u = c[j];
        c[j] = f2add(u, m);
        c[j + 4] = f2sub(u, m);
      }
    }
#pragma unroll
    for (int j = 0; j < 8; ++j) {                 // h=64
      float2 m0 = cmulc(c[j + 8], T64[j & 3]);
      float2 m = (j < 4) ? m0 : PI(m0);
      float2 u = c[j];
      c[j] = f2add(u, m);
      c[j + 8] = f2sub(u, m);
    }
  }
};

// K1: per (b, z1) plane, 512 thr. Row x-FFT (2 rows/group, high halves
// retained in regs); half-plane LDS transpose in two 64-column chunks;
// column y-FFTs written straight to Z(b, x, z1, y) (y-contiguous).
__global__ __launch_bounds__(512) WPEU4 void k_fwd_xy(const float* __restrict__ v1,
                                                      const float* __restrict__ v2,
                                                      float2* __restrict__ Z) {
  __shared__ float2 s[V * P1];   // [row y 0..127][x 0..63], 69632 B
  const int tid = threadIdx.x;
  const int g = tid >> 3, lq = tid & 7;
  const int b = blockIdx.x >> 7, z1 = blockIdx.x & 127;
  WF16 F;
  F.init(lq);
  const int e = F.e;
  const size_t pb = (size_t)b * V3 + (size_t)z1 * V2;
  const size_t g0 = pb + (size_t)g * V, g1 = pb + (size_t)(g + 64) * V;
  float2 c0[16], c1[16];
#pragma unroll
  for (int j = 0; j < 16; ++j) {
    const int n = e + 8 * j;
    c0[j] = make_float2(v1[g0 + n], v2[g0 + n]);
  }
#pragma unroll
  for (int j = 0; j < 16; ++j) {
    const int n = e + 8 * j;
    c1[j] = make_float2(v1[g1 + n], v2[g1 + n]);
  }
  F.fwd(c0);
  F.fwd(c1);
#pragma unroll
  for (int j = 0; j < 8; ++j) s[g * P1 + e + 8 * j] = c0[j];          // x<64
#pragma unroll
  for (int j = 0; j < 8; ++j) s[(g + 64) * P1 + e + 8 * j] = c1[j];
  __syncthreads();
  {                                              // columns x = g in [0,64)
    float2 d[16];
#pragma unroll
    for (int j = 0; j < 16; ++j) d[j] = s[(e + 8 * j) * P1 + g];
    F.fwd(d);
    const size_t zb = ((size_t)(b * V + g) * V + z1) * V;
#pragma unroll
    for (int j = 0; j < 16; ++j) Z[zb + e + 8 * j] = d[j];
  }
  __syncthreads();
#pragma unroll
  for (int j = 8; j < 16; ++j) s[g * P1 + e + 8 * (j - 8)] = c0[j];   // x>=64
#pragma unroll
  for (int j = 8; j < 16; ++j) s[(g + 64) * P1 + e + 8 * (j - 8)] = c1[j];
  __syncthreads();
  {                                              // columns x = 64+g
    float2 d[16];
#pragma unroll
    for (int j = 0; j < 16; ++j) d[j] = s[(e + 8 * j) * P1 + g];
    F.fwd(d);
    const size_t zb = ((size_t)(b * V + 64 + g) * V + z1) * V;
#pragma unroll
    for (int j = 0; j < 16; ++j) Z[zb + e + 8 * j] = d[j];
  }
}

// K2: per (b, slice-pair). Two 128x32 (z,y) quarter-slices in LDS; fwd z-FFT
// + Hermitian combine + inv z-FFT. Even-ky slices pair same-q; odd-ky slices
// pair q0<->q1 across the x-pair; x in {0,1} self-paired.
__global__ __launch_bounds__(512) WPEU4 void k_z_fused(float2* __restrict__ Z) {
  __shared__ float2 T[2 * SLICE];   // 69632 B -> 2 blocks/CU
  const int tid = threadIdx.x, lane = tid & 63, wave = tid >> 6;
  const int o = lane >> 3, lq = lane & 7;
  const int blk = blockIdx.x;
  const int b = blk >> 8, idx = blk & 255;
  int x0, x1, jb0, jb1;
  bool within = false;
  {
    const int h = idx >> 7, r2 = idx & 127;   // h = ky parity (storage bit6)
    if (r2 < 126) {
      const int k = (r2 >> 1) + 1, cc = r2 & 1;
      const int xa = bitrev7(k), xb = bitrev7(V - k);
      if (h == 0) { x0 = xa; x1 = xb; jb0 = cc * 32; jb1 = cc * 32; }
      else { x0 = cc ? xb : xa; x1 = cc ? xa : xb; jb0 = 64; jb1 = 96; }
    } else {
      x0 = x1 = r2 - 126;                     // self-paired x = 0 or 1
      if (h == 0) { jb0 = 0; jb1 = 32; within = true; }
      else { jb0 = 64; jb1 = 96; }
    }
  }
  WF16 F;
  F.init(lq);
  const int e = F.e;
  const size_t base0 = (size_t)(b * V + x0) * V2 + jb0;
  const size_t base1 = (size_t)(b * V + x1) * V2 + jb1;

  for (int p = tid; p < 2048; p += 512) {       // stage in
    const int z = p >> 4, w = (p & 15) << 1;
    *(float4*)&T[z * PH3 + w] = *(const float4*)&Z[base0 + (size_t)z * V + w];
  }
  for (int p = tid; p < 2048; p += 512) {
    const int z = p >> 4, w = (p & 15) << 1;
    *(float4*)&T[SLICE + z * PH3 + w] =
        *(const float4*)&Z[base1 + (size_t)z * V + w];
  }
  __syncthreads();

  const int col = wave * 8 + o;                 // 0..63: 2 slices x 32 cols
  const int tb = (col >> 5) * SLICE, yc = col & 31;
  float2 c[16];
#pragma unroll
  for (int j = 0; j < 16; ++j) c[j] = T[tb + (e + 8 * j) * PH3 + yc];
  F.fwd(c);
#pragma unroll
  for (int j = 0; j < 16; ++j) T[tb + (e + 8 * j) * PH3 + yc] = c[j];
  __syncthreads();

  if (!within) {                                // combine S0 <-> S1
    for (int p = tid; p < 4096; p += 512) {
      const int z = p >> 5, t = p & 31;
      const int zm = negrev(z), tm = negrev(jb0 + t) & 31;
      const float2 a  = T[z * PH3 + t];
      const float2 bb = T[SLICE + zm * PH3 + tm];
      const float f1r = 0.5f * (a.x + bb.x), f1i = 0.5f * (a.y - bb.y);
      const float f2r = 0.5f * (a.y + bb.y), f2i = 0.5f * (bb.x - a.x);
      const float gr = f1r * f2r + f1i * f2i;
      const float gi = f1i * f2r - f1r * f2i;
      T[z * PH3 + t] = make_float2(gr, gi);
      T[SLICE + zm * PH3 + tm] = make_float2(gr, -gi);
    }
  } else {                                      // combine within each slice
    for (int p = tid; p < 8192; p += 512) {
      const int s2 = p >> 12, z = (p >> 5) & 127, t = p & 31;
      const int zm = negrev(z), tm = negrev(s2 * 32 + t) & 31;
      const int pl = z * 32 + t, pm = zm * 32 + tm;
      if (pm < pl) continue;
      const float2 a  = T[s2 * SLICE + z * PH3 + t];
      const float2 bb = T[s2 * SLICE + zm * PH3 + tm];
      const float f1r = 0.5f * (a.x + bb.x), f1i = 0.5f * (a.y - bb.y);
      const float f2r = 0.5f * (a.y + bb.y), f2i = 0.5f * (bb.x - a.x);
      const float gr = f1r * f2r + f1i * f2i;
      const float gi = f1i * f2r - f1r * f2i;
      T[s2 * SLICE + z * PH3 + t] = make_float2(gr, gi);
      if (pm != pl) T[s2 * SLICE + zm * PH3 + tm] = make_float2(gr, -gi);
    }
  }
  __syncthreads();

#pragma unroll
  for (int j = 0; j < 16; ++j) c[j] = T[tb + (e + 8 * j) * PH3 + yc];
  F.inv(c);
#pragma unroll
  for (int j = 0; j < 16; ++j) T[tb + (e + 8 * j) * PH3 + yc] = c[j];
  __syncthreads();

  for (int p = tid; p < 2048; p += 512) {       // stage out
    const int z = p >> 4, w = (p & 15) << 1;
    *(float4*)&Z[base0 + (size_t)z * V + w] = *(const float4*)&T[z * PH3 + w];
  }
  for (int p = tid; p < 2048; p += 512) {
    const int z = p >> 4, w = (p & 15) << 1;
    *(float4*)&Z[base1 + (size_t)z * V + w] =
        *(const float4*)&T[SLICE + z * PH3 + w];
  }
}

// K3: per (b, z1) plane, 512 thr. Inverse y-FFT of 2 x-lines/group (high
// halves retained in regs); half-plane LDS transpose in two 64-row chunks;
// inverse x-FFT rows; real part * 1/V^3 to out(b, z1, y, x).
__global__ __launch_bounds__(512) WPEU4 void k_inv_xy(const float2* __restrict__ Z,
                                                      float* __restrict__ out) {
  __shared__ float2 s[64 * P3];  // [y-half 0..63][x 0..127], 67584 B
  const int tid = threadIdx.x;
  const int g = tid >> 3, lq = tid & 7;
  const int b = blockIdx.x >> 7, z1 = blockIdx.x & 127;
  WF16 F;
  F.init(lq);
  const int e = F.e;
  const int x0 = g, x1 = g + 64;
  const size_t zb0 = ((size_t)(b * V + x0) * V + z1) * V;
  const size_t zb1 = ((size_t)(b * V + x1) * V + z1) * V;
  float2 c0[16], c1[16];
#pragma unroll
  for (int j = 0; j < 16; ++j) c0[j] = Z[zb0 + e + 8 * j];
#pragma unroll
  for (int j = 0; j < 16; ++j) c1[j] = Z[zb1 + e + 8 * j];
  F.inv(c0);
  F.inv(c1);
#pragma unroll
  for (int j = 0; j < 8; ++j) s[(e + 8 * j) * P3 + x0] = c0[j];       // y<64
#pragma unroll
  for (int j = 0; j < 8; ++j) s[(e + 8 * j) * P3 + x1] = c1[j];
  __syncthreads();
  const float sc = 1.0f / 2097152.0f;  // 1/V^3
  {                                              // rows y = g in [0,64)
    float2 d[16];
#pragma unroll
    for (int j = 0; j < 16; ++j) d[j] = s[g * P3 + e + 8 * j];
    F.inv(d);
    const size_t gg = (size_t)b * V3 + (size_t)z1 * V2 + (size_t)g * V;
#pragma unroll
    for (int j = 0; j < 16; ++j) out[gg + e + 8 * j] = d[j].x * sc;
  }
  __syncthreads();
#pragma unroll
  for (int j = 8; j < 16; ++j) s[(e + 8 * (j - 8)) * P3 + x0] = c0[j];  // y>=64
#pragma unroll
  for (int j = 8; j < 16; ++j) s[(e + 8 * (j - 8)) * P3 + x1] = c1[j];
  __syncthreads();
  {                                              // rows y = 64+g
    float2 d[16];
#pragma unroll
    for (int j = 0; j < 16; ++j) d[j] = s[g * P3 + e + 8 * j];
    F.inv(d);
    const size_t gg = (size_t)b * V3 + (size_t)z1 * V2 + (size_t)(64 + g) * V;
#pragma unroll
    for (int j = 0; j < 16; ++j) out[gg + e + 8 * j] = d[j].x * sc;
  }
}

extern "C" void kernel_launch(void* const* d_in, const int* in_sizes, int n_in,
                              void* d_out, int out_size, void* d_ws, size_t ws_size,
                              hipStream_t stream) {
  const float* v1 = (const float*)d_in[0];
  const float* v2 = (const float*)d_in[1];
  float* out = (float*)d_out;
  float2* Z  = (float2*)d_ws;  // NB*V3*8 = 128 MiB

  k_fwd_xy<<<NB * V, 512, 0, stream>>>(v1, v2, Z);
  k_z_fused<<<NB * 256, 512, 0, stream>>>(Z);   // 2 quarter-slices per block
  k_inv_xy<<<NB * V, 512, 0, stream>>>(Z, out);
}

// Round 5
// 333.870 us; speedup vs baseline: 1.0368x; 1.0368x over previous
//
#include <hip/hip_runtime.h>
#include <math.h>

// Circular 3D cross-correlation via FFT, B=8, V=128.
// Z = v1 + i*v2 packed complex FFT; Hermitian split; G = F1*conj(F2); inverse.
// Storage: each transformed axis in bit-reversed order; pairs k<->-k via
// bitrev7 per axis (same convention as all passing rounds).
//
// Round-8 mechanics:
//  * Counters showed global-store write amplification: K1 wrote 186 MB for
//    134 MB of Z (64-B store granule/group), K3 wrote 226 MB for 67 MB of out
//    (32-B granule), while K2's full-line float4 stores were bit-exact.
//    Fix: K1/K3 final results now bounce through LDS and are stored
//    WAVE-COOPERATIVELY -- each wave writes a contiguous 1-KB Z x-line
//    (lane=float4) or 512-B out row (lane=float2) per instruction: full
//    128-B-line coverage, no read-modify-write.
//  * Otherwise round-6/7 structure: K1/K3 512 thr, half-plane LDS, register
//    retention of high halves; K2 quarter-slice pairs; 2 blocks/CU everywhere.
//  * FFT core (WF16) unchanged: 16 elem/lane, DPP-only cross-lane stages.

#define V    128
#define V2   16384
#define V3   2097152
#define NB   8
#define P1   68             // K1 LDS pitch (float2): [128 rows][64 x], 2P%32==8
#define PL1  130            // K1 line-buffer pitch (float2): [64 lines][128 y]
#define P3   132            // K3 LDS pitch (float2): [64 y][128 x],  2P%32==8
#define PL3  132            // K3 row-buffer pitch (float): [64 rows][128 x]
#define PH3  34             // K2 LDS pitch (float2) for 32-wide slices
#define SLICE (V * PH3)     // 4352 float2 = 34816 B

#define WPEU4 __attribute__((amdgpu_waves_per_eu(4, 4)))

__device__ __forceinline__ int bitrev7(int x) {
  return (int)(__brev((unsigned)x) >> 25);
}
__device__ __forceinline__ int negrev(int j) {
  int k = bitrev7(j);
  return bitrev7((V - k) & (V - 1));
}

__device__ __forceinline__ float2 cmul(float2 a, float2 b) {
  return make_float2(a.x * b.x - a.y * b.y, a.x * b.y + a.y * b.x);
}
__device__ __forceinline__ float2 cmulc(float2 a, float2 b) {  // a * conj(b)
  return make_float2(a.x * b.x + a.y * b.y, a.y * b.x - a.x * b.y);
}
__device__ __forceinline__ float2 csqr(float2 a) {
  return make_float2(a.x * a.x - a.y * a.y, 2.0f * a.x * a.y);
}
__device__ __forceinline__ float2 f2add(float2 a, float2 b) {
  return make_float2(a.x + b.x, a.y + b.y);
}
__device__ __forceinline__ float2 f2sub(float2 a, float2 b) {
  return make_float2(a.x - b.x, a.y - b.y);
}
__device__ __forceinline__ float2 NI(float2 z) { return make_float2(z.y, -z.x); }  // z*(-i)
__device__ __forceinline__ float2 PI(float2 z) { return make_float2(-z.y, z.x); }  // z*(+i)

// DPP lane exchange: 0xB1 = quad_perm[1,0,3,2] (lane^1),
// 0x4E = quad_perm[2,3,0,1] (lane^2), 0x141 = row_half_mirror (lane^7).
template <int CTRL>
__device__ __forceinline__ float dppf(float v) {
  return __int_as_float(
      __builtin_amdgcn_update_dpp(0, __float_as_int(v), CTRL, 0xF, 0xF, true));
}
template <int CTRL>
__device__ __forceinline__ float2 dpp2(float2 v) {
  return make_float2(dppf<CTRL>(v.x), dppf<CTRL>(v.y));
}

// 128-pt radix-2 FFT: lane lq (0..7 in group) holds elements n = e + 8j,
// j=0..15, e = lq ^ 3*bit2(lq). Fwd DIF h=64..8 in-lane, h=4,2,1 via DPP.
// Inv DIT mirrored with conjugated twiddles (cmulc on the same table).
struct WF16 {
  float2 T64[4], T32[2], T16a, T16b, T8w, ts4, ts2;
  float sg4, sg2, sg1;
  bool up4, up2;
  int e;

  __device__ void init(int lq) {
    e = lq ^ (((lq >> 2) & 1) * 3);
    const float k = -6.28318530717958647692f / 128.0f;
    float2 w1 = make_float2(cosf(k * (float)e), sinf(k * (float)e));  // W128^e
    const float C1 = 0.92387953251128675613f;   // cos(pi/8)
    const float S1 = 0.38268343236508977173f;   // sin(pi/8)
    const float R  = 0.70710678118654752440f;
    T64[0] = w1;                                  // W128^{e+8j} = w1*W16^j
    T64[1] = cmul(w1, make_float2(C1, -S1));
    T64[2] = cmul(w1, make_float2(R, -R));
    T64[3] = cmul(w1, make_float2(S1, -C1));      // j>=4 derived via *(-i)
    float2 w2 = csqr(w1);                         // W128^{2e}
    T32[0] = w2;
    T32[1] = cmul(w2, make_float2(R, -R));        // j0>=2 derived via *(-i)
    T16a = csqr(w2);                              // W128^{4e}
    T16b = NI(T16a);                              // W128^{4e+32}
    T8w = csqr(T16a);                             // W128^{8e}
    up4 = (e >> 2) & 1;
    up2 = (e >> 1) & 1;
    const bool up1 = e & 1;
    sg4 = up4 ? -1.0f : 1.0f;
    sg2 = up2 ? -1.0f : 1.0f;
    sg1 = up1 ? -1.0f : 1.0f;
    const int m4 = e & 3;
    float2 w8p = (m4 == 0) ? make_float2(1.0f, 0.0f)
               : (m4 == 1) ? make_float2(R, -R)
               : (m4 == 2) ? make_float2(0.0f, -1.0f)
                           : make_float2(-R, -R);
    ts4 = up4 ? w8p : make_float2(1.0f, 0.0f);    // W8^{e&3} on upper half
    ts2 = (up2 && (e & 1)) ? make_float2(0.0f, -1.0f) : make_float2(1.0f, 0.0f);
  }

  __device__ __forceinline__ void fwd(float2 c[16]) const {
#pragma unroll
    for (int j = 0; j < 8; ++j) {                 // h=64
      float2 u = c[j], v = c[j + 8];
      c[j] = f2add(u, v);
      float2 t = cmul(f2sub(u, v), T64[j & 3]);
      c[j + 8] = (j < 4) ? t : NI(t);
    }
#pragma unroll
    for (int g = 0; g < 2; ++g) {                 // h=32
#pragma unroll
      for (int j0 = 0; j0 < 4; ++j0) {
        const int j = g * 8 + j0;
        float2 u = c[j], v = c[j + 4];
        c[j] = f2add(u, v);
        float2 t = cmul(f2sub(u, v), T32[j0 & 1]);
        c[j + 4] = (j0 < 2) ? t : NI(t);
      }
    }
#pragma unroll
    for (int g = 0; g < 4; ++g) {                 // h=16
#pragma unroll
      for (int j0 = 0; j0 < 2; ++j0) {
        const int j = g * 4 + j0;
        float2 u = c[j], v = c[j + 2];
        c[j] = f2add(u, v);
        c[j + 2] = cmul(f2sub(u, v), j0 ? T16b : T16a);
      }
    }
#pragma unroll
    for (int j = 0; j < 16; j += 2) {             // h=8
      float2 u = c[j], v = c[j + 1];
      c[j] = f2add(u, v);
      c[j + 1] = cmul(f2sub(u, v), T8w);
    }
#pragma unroll
    for (int j = 0; j < 16; ++j) {                // h=4 : lane^7
      float2 p = dpp2<0x141>(c[j]);
      float2 t = make_float2(fmaf(c[j].x, sg4, p.x), fmaf(c[j].y, sg4, p.y));
      c[j] = cmul(t, ts4);
    }
#pragma unroll
    for (int j = 0; j < 16; ++j) {                // h=2 : lane^2
      float2 p = dpp2<0x4E>(c[j]);
      float2 t = make_float2(fmaf(c[j].x, sg2, p.x), fmaf(c[j].y, sg2, p.y));
      c[j] = cmul(t, ts2);
    }
#pragma unroll
    for (int j = 0; j < 16; ++j) {                // h=1 : lane^1 (tw = 1)
      float2 p = dpp2<0xB1>(c[j]);
      c[j] = make_float2(fmaf(c[j].x, sg1, p.x), fmaf(c[j].y, sg1, p.y));
    }
  }

  __device__ __forceinline__ void inv(float2 c[16]) const {
#pragma unroll
    for (int j = 0; j < 16; ++j) {                // h=1
      float2 p = dpp2<0xB1>(c[j]);
      c[j] = make_float2(fmaf(c[j].x, sg1, p.x), fmaf(c[j].y, sg1, p.y));
    }
#pragma unroll
    for (int j = 0; j < 16; ++j) {                // h=2
      float2 m = cmulc(c[j], ts2);
      float2 q = make_float2(up2 ? m.x : c[j].x, up2 ? m.y : c[j].y);
      float2 p = dpp2<0x4E>(q);
      c[j] = make_float2(fmaf(q.x, sg2, p.x), fmaf(q.y, sg2, p.y));
    }
#pragma unroll
    for (int j = 0; j < 16; ++j) {                // h=4
      float2 m = cmulc(c[j], ts4);
      float2 q = make_float2(up4 ? m.x : c[j].x, up4 ? m.y : c[j].y);
      float2 p = dpp2<0x141>(q);
      c[j] = make_float2(fmaf(q.x, sg4, p.x), fmaf(q.y, sg4, p.y));
    }
#pragma unroll
    for (int j = 0; j < 16; j += 2) {             // h=8
      float2 m = cmulc(c[j + 1], T8w);
      float2 u = c[j];
      c[j] = f2add(u, m);
      c[j + 1] = f2sub(u, m);
    }
#pragma unroll
    for (int g = 0; g < 4; ++g) {                 // h=16
#pragma unroll
      for (int j0 = 0; j0 < 2; ++j0) {
        const int j = g * 4 + j0;
        float2 m = cmulc(c[j + 2], j0 ? T16b : T16a);
        float2 u = c[j];
        c[j] = f2add(u, m);
        c[j + 2] = f2sub(u, m);
      }
    }
#pragma unroll
    for (int g = 0; g < 2; ++g) {                 // h=32
#pragma unroll
      for (int j0 = 0; j0 < 4; ++j0) {
        const int j = g * 8 + j0;
        float2 m0 = cmulc(c[j + 4], T32[j0 & 1]);
        float2 m = (j0 < 2) ? m0 : PI(m0);        // conj(T*(-i)) = conj(T)*i
        float2 u = c[j];
        c[j] = f2add(u, m);
        c[j + 4] = f2sub(u, m);
      }
    }
#pragma unroll
    for (int j = 0; j < 8; ++j) {                 // h=64
      float2 m0 = cmulc(c[j + 8], T64[j & 3]);
      float2 m = (j < 4) ? m0 : PI(m0);
      float2 u = c[j];
      c[j] = f2add(u, m);
      c[j + 8] = f2sub(u, m);
    }
  }
};

// K1: per (b, z1) plane, 512 thr. Row x-FFT (2 rows/group, high halves
// retained in regs); half-plane LDS transpose in two 64-column chunks;
// column y-FFT results repacked in LDS as x-lines and stored to
// Z(b, x, z1, y) wave-cooperatively (1 KB contiguous per wave instruction).
__global__ __launch_bounds__(512) WPEU4 void k_fwd_xy(const float* __restrict__ v1,
                                                      const float* __restrict__ v2,
                                                      float2* __restrict__ Z) {
  __shared__ float2 s[V * P1];   // 69632 B; aliased as [64 lines][PL1] too
  const int tid = threadIdx.x, lane = tid & 63, wave = tid >> 6;
  const int g = tid >> 3, lq = tid & 7;
  const int b = blockIdx.x >> 7, z1 = blockIdx.x & 127;
  WF16 F;
  F.init(lq);
  const int e = F.e;
  const size_t pb = (size_t)b * V3 + (size_t)z1 * V2;
  const size_t g0 = pb + (size_t)g * V, g1 = pb + (size_t)(g + 64) * V;
  float2 c0[16], c1[16];
#pragma unroll
  for (int j = 0; j < 16; ++j) {
    const int n = e + 8 * j;
    c0[j] = make_float2(v1[g0 + n], v2[g0 + n]);
  }
#pragma unroll
  for (int j = 0; j < 16; ++j) {
    const int n = e + 8 * j;
    c1[j] = make_float2(v1[g1 + n], v2[g1 + n]);
  }
  F.fwd(c0);
  F.fwd(c1);
#pragma unroll
  for (int j = 0; j < 8; ++j) s[g * P1 + e + 8 * j] = c0[j];          // x<64
#pragma unroll
  for (int j = 0; j < 8; ++j) s[(g + 64) * P1 + e + 8 * j] = c1[j];
  __syncthreads();
  {                                              // columns x = g in [0,64)
    float2 d[16];
#pragma unroll
    for (int j = 0; j < 16; ++j) d[j] = s[(e + 8 * j) * P1 + g];
    F.fwd(d);
    __syncthreads();                             // all col reads of s done
#pragma unroll
    for (int j = 0; j < 16; ++j) s[g * PL1 + e + 8 * j] = d[j];  // line x=g
  }
  __syncthreads();
  for (int line = wave; line < 64; line += 8) {  // full 1-KB line per wave
    const size_t zb = ((size_t)(b * V + line) * V + z1) * V;
    *(float4*)&Z[zb + 2 * lane] = *(const float4*)&s[line * PL1 + 2 * lane];
  }
  __syncthreads();
#pragma unroll
  for (int j = 8; j < 16; ++j) s[g * P1 + e + 8 * (j - 8)] = c0[j];   // x>=64
#pragma unroll
  for (int j = 8; j < 16; ++j) s[(g + 64) * P1 + e + 8 * (j - 8)] = c1[j];
  __syncthreads();
  {                                              // columns x = 64+g
    float2 d[16];
#pragma unroll
    for (int j = 0; j < 16; ++j) d[j] = s[(e + 8 * j) * P1 + g];
    F.fwd(d);
    __syncthreads();
#pragma unroll
    for (int j = 0; j < 16; ++j) s[g * PL1 + e + 8 * j] = d[j];
  }
  __syncthreads();
  for (int line = wave; line < 64; line += 8) {
    const size_t zb = ((size_t)(b * V + 64 + line) * V + z1) * V;
    *(float4*)&Z[zb + 2 * lane] = *(const float4*)&s[line * PL1 + 2 * lane];
  }
}

// K2: per (b, slice-pair). Two 128x32 (z,y) quarter-slices in LDS; fwd z-FFT
// + Hermitian combine + inv z-FFT. Even-ky slices pair same-q; odd-ky slices
// pair q0<->q1 across the x-pair; x in {0,1} self-paired.
__global__ __launch_bounds__(512) WPEU4 void k_z_fused(float2* __restrict__ Z) {
  __shared__ float2 T[2 * SLICE];   // 69632 B -> 2 blocks/CU
  const int tid = threadIdx.x, lane = tid & 63, wave = tid >> 6;
  const int o = lane >> 3, lq = lane & 7;
  const int blk = blockIdx.x;
  const int b = blk >> 8, idx = blk & 255;
  int x0, x1, jb0, jb1;
  bool within = false;
  {
    const int h = idx >> 7, r2 = idx & 127;   // h = ky parity (storage bit6)
    if (r2 < 126) {
      const int k = (r2 >> 1) + 1, cc = r2 & 1;
      const int xa = bitrev7(k), xb = bitrev7(V - k);
      if (h == 0) { x0 = xa; x1 = xb; jb0 = cc * 32; jb1 = cc * 32; }
      else { x0 = cc ? xb : xa; x1 = cc ? xa : xb; jb0 = 64; jb1 = 96; }
    } else {
      x0 = x1 = r2 - 126;                     // self-paired x = 0 or 1
      if (h == 0) { jb0 = 0; jb1 = 32; within = true; }
      else { jb0 = 64; jb1 = 96; }
    }
  }
  WF16 F;
  F.init(lq);
  const int e = F.e;
  const size_t base0 = (size_t)(b * V + x0) * V2 + jb0;
  const size_t base1 = (size_t)(b * V + x1) * V2 + jb1;

  for (int p = tid; p < 2048; p += 512) {       // stage in
    const int z = p >> 4, w = (p & 15) << 1;
    *(float4*)&T[z * PH3 + w] = *(const float4*)&Z[base0 + (size_t)z * V + w];
  }
  for (int p = tid; p < 2048; p += 512) {
    const int z = p >> 4, w = (p & 15) << 1;
    *(float4*)&T[SLICE + z * PH3 + w] =
        *(const float4*)&Z[base1 + (size_t)z * V + w];
  }
  __syncthreads();

  const int col = wave * 8 + o;                 // 0..63: 2 slices x 32 cols
  const int tb = (col >> 5) * SLICE, yc = col & 31;
  float2 c[16];
#pragma unroll
  for (int j = 0; j < 16; ++j) c[j] = T[tb + (e + 8 * j) * PH3 + yc];
  F.fwd(c);
#pragma unroll
  for (int j = 0; j < 16; ++j) T[tb + (e + 8 * j) * PH3 + yc] = c[j];
  __syncthreads();

  if (!within) {                                // combine S0 <-> S1
    for (int p = tid; p < 4096; p += 512) {
      const int z = p >> 5, t = p & 31;
      const int zm = negrev(z), tm = negrev(jb0 + t) & 31;
      const float2 a  = T[z * PH3 + t];
      const float2 bb = T[SLICE + zm * PH3 + tm];
      const float f1r = 0.5f * (a.x + bb.x), f1i = 0.5f * (a.y - bb.y);
      const float f2r = 0.5f * (a.y + bb.y), f2i = 0.5f * (bb.x - a.x);
      const float gr = f1r * f2r + f1i * f2i;
      const float gi = f1i * f2r - f1r * f2i;
      T[z * PH3 + t] = make_float2(gr, gi);
      T[SLICE + zm * PH3 + tm] = make_float2(gr, -gi);
    }
  } else {                                      // combine within each slice
    for (int p = tid; p < 8192; p += 512) {
      const int s2 = p >> 12, z = (p >> 5) & 127, t = p & 31;
      const int zm = negrev(z), tm = negrev(s2 * 32 + t) & 31;
      const int pl = z * 32 + t, pm = zm * 32 + tm;
      if (pm < pl) continue;
      const float2 a  = T[s2 * SLICE + z * PH3 + t];
      const float2 bb = T[s2 * SLICE + zm * PH3 + tm];
      const float f1r = 0.5f * (a.x + bb.x), f1i = 0.5f * (a.y - bb.y);
      const float f2r = 0.5f * (a.y + bb.y), f2i = 0.5f * (bb.x - a.x);
      const float gr = f1r * f2r + f1i * f2i;
      const float gi = f1i * f2r - f1r * f2i;
      T[s2 * SLICE + z * PH3 + t] = make_float2(gr, gi);
      if (pm != pl) T[s2 * SLICE + zm * PH3 + tm] = make_float2(gr, -gi);
    }
  }
  __syncthreads();

#pragma unroll
  for (int j = 0; j < 16; ++j) c[j] = T[tb + (e + 8 * j) * PH3 + yc];
  F.inv(c);
#pragma unroll
  for (int j = 0; j < 16; ++j) T[tb + (e + 8 * j) * PH3 + yc] = c[j];
  __syncthreads();

  for (int p = tid; p < 2048; p += 512) {       // stage out
    const int z = p >> 4, w = (p & 15) << 1;
    *(float4*)&Z[base0 + (size_t)z * V + w] = *(const float4*)&T[z * PH3 + w];
  }
  for (int p = tid; p < 2048; p += 512) {
    const int z = p >> 4, w = (p & 15) << 1;
    *(float4*)&Z[base1 + (size_t)z * V + w] =
        *(const float4*)&T[SLICE + z * PH3 + w];
  }
}

// K3: per (b, z1) plane, 512 thr. Inverse y-FFT of 2 x-lines/group (high
// halves retained in regs); half-plane LDS transpose in two 64-row chunks;
// inverse x-FFT rows repacked in LDS (float) and stored to out(b, z1, y, x)
// wave-cooperatively (512 B contiguous per wave instruction).
__global__ __launch_bounds__(512) WPEU4 void k_inv_xy(const float2* __restrict__ Z,
                                                      float* __restrict__ out) {
  __shared__ float2 s[64 * P3];  // 67584 B; low half aliased as float rows
  float* fL = (float*)s;         // [64 rows][PL3] floats = 33792 B
  const int tid = threadIdx.x, lane = tid & 63, wave = tid >> 6;
  const int g = tid >> 3, lq = tid & 7;
  const int b = blockIdx.x >> 7, z1 = blockIdx.x & 127;
  WF16 F;
  F.init(lq);
  const int e = F.e;
  const int x0 = g, x1 = g + 64;
  const size_t zb0 = ((size_t)(b * V + x0) * V + z1) * V;
  const size_t zb1 = ((size_t)(b * V + x1) * V + z1) * V;
  float2 c0[16], c1[16];
#pragma unroll
  for (int j = 0; j < 16; ++j) c0[j] = Z[zb0 + e + 8 * j];
#pragma unroll
  for (int j = 0; j < 16; ++j) c1[j] = Z[zb1 + e + 8 * j];
  F.inv(c0);
  F.inv(c1);
#pragma unroll
  for (int j = 0; j < 8; ++j) s[(e + 8 * j) * P3 + x0] = c0[j];       // y<64
#pragma unroll
  for (int j = 0; j < 8; ++j) s[(e + 8 * j) * P3 + x1] = c1[j];
  __syncthreads();
  const float sc = 1.0f / 2097152.0f;  // 1/V^3
  {                                              // rows y = g in [0,64)
    float2 d[16];
#pragma unroll
    for (int j = 0; j < 16; ++j) d[j] = s[g * P3 + e + 8 * j];
    F.inv(d);
    __syncthreads();                             // all row reads of s done
#pragma unroll
    for (int j = 0; j < 16; ++j) fL[g * PL3 + e + 8 * j] = d[j].x * sc;
  }
  __syncthreads();
  for (int row = wave; row < 64; row += 8) {     // 512-B row per wave instr
    const size_t gg = (size_t)b * V3 + (size_t)z1 * V2 + (size_t)row * V;
    *(float2*)&out[gg + 2 * lane] = *(const float2*)&fL[row * PL3 + 2 * lane];
  }
  __syncthreads();
#pragma unroll
  for (int j = 8; j < 16; ++j) s[(e + 8 * (j - 8)) * P3 + x0] = c0[j];  // y>=64
#pragma unroll
  for (int j = 8; j < 16; ++j) s[(e + 8 * (j - 8)) * P3 + x1] = c1[j];
  __syncthreads();
  {                                              // rows y = 64+g
    float2 d[16];
#pragma unroll
    for (int j = 0; j < 16; ++j) d[j] = s[g * P3 + e + 8 * j];
    F.inv(d);
    __syncthreads();
#pragma unroll
    for (int j = 0; j < 16; ++j) fL[g * PL3 + e + 8 * j] = d[j].x * sc;
  }
  __syncthreads();
  for (int row = wave; row < 64; row += 8) {
    const size_t gg = (size_t)b * V3 + (size_t)z1 * V2 + (size_t)(64 + row) * V;
    *(float2*)&out[gg + 2 * lane] = *(const float2*)&fL[row * PL3 + 2 * lane];
  }
}

extern "C" void kernel_launch(void* const* d_in, const int* in_sizes, int n_in,
                              void* d_out, int out_size, void* d_ws, size_t ws_size,
                              hipStream_t stream) {
  const float* v1 = (const float*)d_in[0];
  const float* v2 = (const float*)d_in[1];
  float* out = (float*)d_out;
  float2* Z  = (float2*)d_ws;  // NB*V3*8 = 128 MiB

  k_fwd_xy<<<NB * V, 512, 0, stream>>>(v1, v2, Z);
  k_z_fused<<<NB * 256, 512, 0, stream>>>(Z);   // 2 quarter-slices per block
  k_inv_xy<<<NB * V, 512, 0, stream>>>(Z, out);
}

// Round 6
// 303.083 us; speedup vs baseline: 1.1422x; 1.1016x over previous
//
#include <hip/hip_runtime.h>
#include <math.h>

// Circular 3D cross-correlation via FFT, B=8, V=128.
// Z = v1 + i*v2 packed complex FFT; Hermitian split; G = F1*conj(F2); inverse.
// Storage: each transformed axis in bit-reversed order; pairs k<->-k via
// bitrev7 per axis (same convention as all passing rounds).
//
// Round-9 mechanics (anti-spill redesign):
//  * Evidence: VGPR pinned at 64 while K1/K3 liveness ~100 -> scratch spills
//    (K1 WRITE 225 MB vs 134 payload even with full-line stores). Fix: no
//    kernel ever holds more than ONE c[16] line + trimmed twiddles.
//  * K1 h-split: first y-DIF stage (rows y,y+64, twiddle W128^y, elementwise
//    in x) commutes with the x-FFT. Grid (b,z1,h); block streams row pairs,
//    combines on the fly, x-FFT128, half-plane LDS transpose, 64-pt y-FFTs
//    (w2-twiddle chain), repack, 512-B full-line cooperative stores.
//    bitrev7(2k+h) = h*64 + bitrev6(k) keeps the storage convention exact.
//  * K3: 1024 thr, full-plane LDS (1 blk/CU), one c[16] per pass, in-row f32
//    repack, 512-B cooperative stores, 2 barriers.
//  * Twiddles trimmed to w1,w2,w4,w8,ts4,ts2 (12 VGPRs); stage constants
//    derived transiently (identical numerics).
//  * K2 unchanged structurally (quarter-slice pairs, 512 thr, 2 blk/CU).

#define V    128
#define V2   16384
#define V3   2097152
#define NB   8
#define PR1  134            // K1 rows pitch (float2): [64][134] = 68608 B
#define PC1  66             // K1 repack pitch (float2): [128][66] (aliased)
#define PR3  134            // K3 plane pitch (float2): [128][134] = 137216 B
#define PH3  34             // K2 LDS pitch (float2) for 32-wide slices
#define SLICE (V * PH3)     // 4352 float2 = 34816 B

__device__ __forceinline__ int bitrev7(int x) {
  return (int)(__brev((unsigned)x) >> 25);
}
__device__ __forceinline__ int negrev(int j) {
  int k = bitrev7(j);
  return bitrev7((V - k) & (V - 1));
}

__device__ __forceinline__ float2 cmul(float2 a, float2 b) {
  return make_float2(a.x * b.x - a.y * b.y, a.x * b.y + a.y * b.x);
}
__device__ __forceinline__ float2 cmulc(float2 a, float2 b) {  // a * conj(b)
  return make_float2(a.x * b.x + a.y * b.y, a.y * b.x - a.x * b.y);
}
__device__ __forceinline__ float2 csqr(float2 a) {
  return make_float2(a.x * a.x - a.y * a.y, 2.0f * a.x * a.y);
}
__device__ __forceinline__ float2 f2add(float2 a, float2 b) {
  return make_float2(a.x + b.x, a.y + b.y);
}
__device__ __forceinline__ float2 f2sub(float2 a, float2 b) {
  return make_float2(a.x - b.x, a.y - b.y);
}
__device__ __forceinline__ float2 NI(float2 z) { return make_float2(z.y, -z.x); }  // z*(-i)
__device__ __forceinline__ float2 PI(float2 z) { return make_float2(-z.y, z.x); }  // z*(+i)

#define KC1 0.92387953251128675613f   // cos(pi/8)
#define KS1 0.38268343236508977173f   // sin(pi/8)
#define KR  0.70710678118654752440f

// DPP lane exchange: 0xB1 = quad_perm[1,0,3,2] (lane^1),
// 0x4E = quad_perm[2,3,0,1] (lane^2), 0x141 = row_half_mirror (lane^7).
template <int CTRL>
__device__ __forceinline__ float dppf(float v) {
  return __int_as_float(
      __builtin_amdgcn_update_dpp(0, __float_as_int(v), CTRL, 0xF, 0xF, true));
}
template <int CTRL>
__device__ __forceinline__ float2 dpp2(float2 v) {
  return make_float2(dppf<CTRL>(v.x), dppf<CTRL>(v.y));
}

// FFT cores, trimmed twiddle state. Lane lq (0..7 in group) holds elements
// n = e + 8j, e = lq ^ 3*bit2(lq). 128-pt: j=0..15; 64-pt: j=0..7.
// Cross-lane stages h=4,2,1 via DPP masks 7,2,1 (shared by both sizes).
struct WFT {
  float2 w1, w2, w4, w8, ts4, ts2;
  float sg4, sg2, sg1;
  bool up4, up2;
  int e;

  __device__ void init(int lq) {
    e = lq ^ (((lq >> 2) & 1) * 3);
    const float k = -6.28318530717958647692f / 128.0f;
    w1 = make_float2(cosf(k * (float)e), sinf(k * (float)e));  // W128^e
    w2 = csqr(w1);                                             // W64^e
    w4 = csqr(w2);                                             // W32^e
    w8 = csqr(w4);                                             // W16^e
    up4 = (e >> 2) & 1;
    up2 = (e >> 1) & 1;
    const bool up1 = e & 1;
    sg4 = up4 ? -1.0f : 1.0f;
    sg2 = up2 ? -1.0f : 1.0f;
    sg1 = up1 ? -1.0f : 1.0f;
    const int m4 = e & 3;
    float2 w8p = (m4 == 0) ? make_float2(1.0f, 0.0f)
               : (m4 == 1) ? make_float2(KR, -KR)
               : (m4 == 2) ? make_float2(0.0f, -1.0f)
                           : make_float2(-KR, -KR);
    ts4 = up4 ? w8p : make_float2(1.0f, 0.0f);    // W8^{e&3} on upper half
    ts2 = (up2 && (e & 1)) ? make_float2(0.0f, -1.0f) : make_float2(1.0f, 0.0f);
  }

  // -- cross-lane stage helpers (shared fwd/inv shapes) --
  __device__ __forceinline__ void xf4(float2* c, int n) const {
#pragma unroll
    for (int j = 0; j < n; ++j) {                 // h=4 : lane^7
      float2 p = dpp2<0x141>(c[j]);
      float2 t = make_float2(fmaf(c[j].x, sg4, p.x), fmaf(c[j].y, sg4, p.y));
      c[j] = cmul(t, ts4);
    }
#pragma unroll
    for (int j = 0; j < n; ++j) {                 // h=2 : lane^2
      float2 p = dpp2<0x4E>(c[j]);
      float2 t = make_float2(fmaf(c[j].x, sg2, p.x), fmaf(c[j].y, sg2, p.y));
      c[j] = cmul(t, ts2);
    }
#pragma unroll
    for (int j = 0; j < n; ++j) {                 // h=1 : lane^1 (tw = 1)
      float2 p = dpp2<0xB1>(c[j]);
      c[j] = make_float2(fmaf(c[j].x, sg1, p.x), fmaf(c[j].y, sg1, p.y));
    }
  }
  __device__ __forceinline__ void xi4(float2* c, int n) const {
#pragma unroll
    for (int j = 0; j < n; ++j) {                 // h=1
      float2 p = dpp2<0xB1>(c[j]);
      c[j] = make_float2(fmaf(c[j].x, sg1, p.x), fmaf(c[j].y, sg1, p.y));
    }
#pragma unroll
    for (int j = 0; j < n; ++j) {                 // h=2
      float2 m = cmulc(c[j], ts2);
      float2 q = make_float2(up2 ? m.x : c[j].x, up2 ? m.y : c[j].y);
      float2 p = dpp2<0x4E>(q);
      c[j] = make_float2(fmaf(q.x, sg2, p.x), fmaf(q.y, sg2, p.y));
    }
#pragma unroll
    for (int j = 0; j < n; ++j) {                 // h=4
      float2 m = cmulc(c[j], ts4);
      float2 q = make_float2(up4 ? m.x : c[j].x, up4 ? m.y : c[j].y);
      float2 p = dpp2<0x141>(q);
      c[j] = make_float2(fmaf(q.x, sg4, p.x), fmaf(q.y, sg4, p.y));
    }
  }

  __device__ __forceinline__ void fwd128(float2 c[16]) const {
    const float2 tA = cmul(w1, make_float2(KC1, -KS1));
    const float2 tB = cmul(w1, make_float2(KR, -KR));
    const float2 tC = cmul(w1, make_float2(KS1, -KC1));
#pragma unroll
    for (int j = 0; j < 8; ++j) {                 // h=64
      float2 u = c[j], v = c[j + 8];
      c[j] = f2add(u, v);
      const int q = j & 3;
      float2 tw = (q == 0) ? w1 : (q == 1) ? tA : (q == 2) ? tB : tC;
      float2 t = cmul(f2sub(u, v), tw);
      c[j + 8] = (j < 4) ? t : NI(t);
    }
    const float2 t2 = cmul(w2, make_float2(KR, -KR));
#pragma unroll
    for (int g = 0; g < 2; ++g) {                 // h=32
#pragma unroll
      for (int j0 = 0; j0 < 4; ++j0) {
        const int j = g * 8 + j0;
        float2 u = c[j], v = c[j + 4];
        c[j] = f2add(u, v);
        float2 t = cmul(f2sub(u, v), (j0 & 1) ? t2 : w2);
        c[j + 4] = (j0 < 2) ? t : NI(t);
      }
    }
    const float2 w4n = NI(w4);
#pragma unroll
    for (int g = 0; g < 4; ++g) {                 // h=16
#pragma unroll
      for (int j0 = 0; j0 < 2; ++j0) {
        const int j = g * 4 + j0;
        float2 u = c[j], v = c[j + 2];
        c[j] = f2add(u, v);
        c[j + 2] = cmul(f2sub(u, v), j0 ? w4n : w4);
      }
    }
#pragma unroll
    for (int j = 0; j < 16; j += 2) {             // h=8
      float2 u = c[j], v = c[j + 1];
      c[j] = f2add(u, v);
      c[j + 1] = cmul(f2sub(u, v), w8);
    }
    xf4(c, 16);
  }

  __device__ __forceinline__ void inv128(float2 c[16]) const {
    xi4(c, 16);
#pragma unroll
    for (int j = 0; j < 16; j += 2) {             // h=8
      float2 m = cmulc(c[j + 1], w8);
      float2 u = c[j];
      c[j] = f2add(u, m);
      c[j + 1] = f2sub(u, m);
    }
#pragma unroll
    for (int g = 0; g < 4; ++g) {                 // h=16
#pragma unroll
      for (int j0 = 0; j0 < 2; ++j0) {
        const int j = g * 4 + j0;
        float2 m0 = cmulc(c[j + 2], w4);
        float2 m = j0 ? PI(m0) : m0;              // conj(NI(w4)) = conj(w4)*i
        float2 u = c[j];
        c[j] = f2add(u, m);
        c[j + 2] = f2sub(u, m);
      }
    }
    const float2 t2 = cmul(w2, make_float2(KR, -KR));
#pragma unroll
    for (int g = 0; g < 2; ++g) {                 // h=32
#pragma unroll
      for (int j0 = 0; j0 < 4; ++j0) {
        const int j = g * 8 + j0;
        float2 m0 = cmulc(c[j + 4], (j0 & 1) ? t2 : w2);
        float2 m = (j0 < 2) ? m0 : PI(m0);
        float2 u = c[j];
        c[j] = f2add(u, m);
        c[j + 4] = f2sub(u, m);
      }
    }
    const float2 tA = cmul(w1, make_float2(KC1, -KS1));
    const float2 tB = cmul(w1, make_float2(KR, -KR));
    const float2 tC = cmul(w1, make_float2(KS1, -KC1));
#pragma unroll
    for (int j = 0; j < 8; ++j) {                 // h=64
      const int q = j & 3;
      float2 tw = (q == 0) ? w1 : (q == 1) ? tA : (q == 2) ? tB : tC;
      float2 m0 = cmulc(c[j + 8], tw);
      float2 m = (j < 4) ? m0 : PI(m0);
      float2 u = c[j];
      c[j] = f2add(u, m);
      c[j + 8] = f2sub(u, m);
    }
  }

  // 64-pt forward DIF on c[8], elements n = e + 8j. Twiddle chain = w2-based
  // (W64^e, W32^e, W16^e); cross stages identical to 128-pt (W8/W4 based).
  __device__ __forceinline__ void fwd64(float2 c[8]) const {
    const float2 t2 = cmul(w2, make_float2(KR, -KR));
#pragma unroll
    for (int j = 0; j < 4; ++j) {                 // h=32
      float2 u = c[j], v = c[j + 4];
      c[j] = f2add(u, v);
      float2 t = cmul(f2sub(u, v), (j & 1) ? t2 : w2);
      c[j + 4] = (j < 2) ? t : NI(t);
    }
    const float2 w4n = NI(w4);
#pragma unroll
    for (int g = 0; g < 2; ++g) {                 // h=16
#pragma unroll
      for (int j0 = 0; j0 < 2; ++j0) {
        const int j = g * 4 + j0;
        float2 u = c[j], v = c[j + 2];
        c[j] = f2add(u, v);
        c[j + 2] = cmul(f2sub(u, v), j0 ? w4n : w4);
      }
    }
#pragma unroll
    for (int j = 0; j < 8; j += 2) {              // h=8
      float2 u = c[j], v = c[j + 1];
      c[j] = f2add(u, v);
      c[j + 1] = cmul(f2sub(u, v), w8);
    }
    xf4(c, 8);
  }
};

// K1: per (b, z1, h). Streams row pairs (y, y+64), applies the first y-DIF
// stage on the fly (h=0: a+b; h=1: (a-b)*W128^y), x-FFT128 per combined row,
// half-plane LDS transpose, 64-pt y-FFT per column, repack, cooperative
// 512-B full-line stores to Z(b, x, z1, h*64 + p).
__global__ __launch_bounds__(512) void k_fwd_xy(const float* __restrict__ v1,
                                                const float* __restrict__ v2,
                                                float2* __restrict__ Z) {
  __shared__ float2 s[64 * PR1];   // 68608 B; repacked as [128][PC1] later
  const int tid = threadIdx.x, lane = tid & 63, wave = tid >> 6;
  const int g = tid >> 3, lq = tid & 7;
  const int bz = blockIdx.x >> 1, h = blockIdx.x & 1;
  const int b = bz >> 7, z1 = bz & 127;
  WFT F;
  F.init(lq);
  const int e = F.e;
  const size_t pb = (size_t)b * V3 + (size_t)z1 * V2;
  const float* __restrict__ a1 = v1 + pb + (size_t)g * V;
  const float* __restrict__ a2 = v2 + pb + (size_t)g * V;
  float2 c[16];
  if (h == 0) {
#pragma unroll
    for (int j = 0; j < 16; ++j) {
      const int n = e + 8 * j;
      c[j] = make_float2(a1[n] + a1[n + 64 * V], a2[n] + a2[n + 64 * V]);
    }
  } else {
    const float kk = -6.28318530717958647692f / 128.0f;
    const float2 Wg = make_float2(cosf(kk * (float)g), sinf(kk * (float)g));
#pragma unroll
    for (int j = 0; j < 16; ++j) {
      const int n = e + 8 * j;
      float2 d = make_float2(a1[n] - a1[n + 64 * V], a2[n] - a2[n + 64 * V]);
      c[j] = cmul(d, Wg);
    }
  }
  F.fwd128(c);
#pragma unroll
  for (int j = 0; j < 16; ++j) s[g * PR1 + e + 8 * j] = c[j];
  __syncthreads();
  float2 ca[8], cb[8];                       // columns x = g and g+64
#pragma unroll
  for (int j = 0; j < 8; ++j) {
    const int r = e + 8 * j;
    ca[j] = s[r * PR1 + g];
    cb[j] = s[r * PR1 + g + 64];
  }
  __syncthreads();                           // all column reads done
  F.fwd64(ca);
  F.fwd64(cb);
#pragma unroll
  for (int j = 0; j < 8; ++j) {              // repack: [x][p] lines
    s[g * PC1 + e + 8 * j] = ca[j];
    s[(g + 64) * PC1 + e + 8 * j] = cb[j];
  }
  __syncthreads();
  for (int L = wave; L < 128; L += 8) {      // 512-B full-line store per wave
    const size_t zb = ((size_t)(b * V + L) * V + z1) * V + h * 64;
    Z[zb + lane] = s[L * PC1 + lane];
  }
}

// K2: per (b, slice-pair). Two 128x32 (z,y) quarter-slices in LDS; fwd z-FFT
// + Hermitian combine + inv z-FFT. Even-ky slices pair same-q; odd-ky slices
// pair q0<->q1 across the x-pair; x in {0,1} self-paired.
__global__ __launch_bounds__(512) void k_z_fused(float2* __restrict__ Z) {
  __shared__ float2 T[2 * SLICE];   // 69632 B -> 2 blocks/CU
  const int tid = threadIdx.x, lane = tid & 63, wave = tid >> 6;
  const int o = lane >> 3, lq = lane & 7;
  const int blk = blockIdx.x;
  const int b = blk >> 8, idx = blk & 255;
  int x0, x1, jb0, jb1;
  bool within = false;
  {
    const int h = idx >> 7, r2 = idx & 127;   // h = ky parity (storage bit6)
    if (r2 < 126) {
      const int k = (r2 >> 1) + 1, cc = r2 & 1;
      const int xa = bitrev7(k), xb = bitrev7(V - k);
      if (h == 0) { x0 = xa; x1 = xb; jb0 = cc * 32; jb1 = cc * 32; }
      else { x0 = cc ? xb : xa; x1 = cc ? xa : xb; jb0 = 64; jb1 = 96; }
    } else {
      x0 = x1 = r2 - 126;                     // self-paired x = 0 or 1
      if (h == 0) { jb0 = 0; jb1 = 32; within = true; }
      else { jb0 = 64; jb1 = 96; }
    }
  }
  WFT F;
  F.init(lq);
  const int e = F.e;
  const size_t base0 = (size_t)(b * V + x0) * V2 + jb0;
  const size_t base1 = (size_t)(b * V + x1) * V2 + jb1;

  for (int p = tid; p < 2048; p += 512) {       // stage in
    const int z = p >> 4, w = (p & 15) << 1;
    *(float4*)&T[z * PH3 + w] = *(const float4*)&Z[base0 + (size_t)z * V + w];
  }
  for (int p = tid; p < 2048; p += 512) {
    const int z = p >> 4, w = (p & 15) << 1;
    *(float4*)&T[SLICE + z * PH3 + w] =
        *(const float4*)&Z[base1 + (size_t)z * V + w];
  }
  __syncthreads();

  const int col = wave * 8 + o;                 // 0..63: 2 slices x 32 cols
  const int tb = (col >> 5) * SLICE, yc = col & 31;
  float2 c[16];
#pragma unroll
  for (int j = 0; j < 16; ++j) c[j] = T[tb + (e + 8 * j) * PH3 + yc];
  F.fwd128(c);
#pragma unroll
  for (int j = 0; j < 16; ++j) T[tb + (e + 8 * j) * PH3 + yc] = c[j];
  __syncthreads();

  if (!within) {                                // combine S0 <-> S1
    for (int p = tid; p < 4096; p += 512) {
      const int z = p >> 5, t = p & 31;
      const int zm = negrev(z), tm = negrev(jb0 + t) & 31;
      const float2 a  = T[z * PH3 + t];
      const float2 bb = T[SLICE + zm * PH3 + tm];
      const float f1r = 0.5f * (a.x + bb.x), f1i = 0.5f * (a.y - bb.y);
      const float f2r = 0.5f * (a.y + bb.y), f2i = 0.5f * (bb.x - a.x);
      const float gr = f1r * f2r + f1i * f2i;
      const float gi = f1i * f2r - f1r * f2i;
      T[z * PH3 + t] = make_float2(gr, gi);
      T[SLICE + zm * PH3 + tm] = make_float2(gr, -gi);
    }
  } else {                                      // combine within each slice
    for (int p = tid; p < 8192; p += 512) {
      const int s2 = p >> 12, z = (p >> 5) & 127, t = p & 31;
      const int zm = negrev(z), tm = negrev(s2 * 32 + t) & 31;
      const int pl = z * 32 + t, pm = zm * 32 + tm;
      if (pm < pl) continue;
      const float2 a  = T[s2 * SLICE + z * PH3 + t];
      const float2 bb = T[s2 * SLICE + zm * PH3 + tm];
      const float f1r = 0.5f * (a.x + bb.x), f1i = 0.5f * (a.y - bb.y);
      const float f2r = 0.5f * (a.y + bb.y), f2i = 0.5f * (bb.x - a.x);
      const float gr = f1r * f2r + f1i * f2i;
      const float gi = f1i * f2r - f1r * f2i;
      T[s2 * SLICE + z * PH3 + t] = make_float2(gr, gi);
      if (pm != pl) T[s2 * SLICE + zm * PH3 + tm] = make_float2(gr, -gi);
    }
  }
  __syncthreads();

#pragma unroll
  for (int j = 0; j < 16; ++j) c[j] = T[tb + (e + 8 * j) * PH3 + yc];
  F.inv128(c);
#pragma unroll
  for (int j = 0; j < 16; ++j) T[tb + (e + 8 * j) * PH3 + yc] = c[j];
  __syncthreads();

  for (int p = tid; p < 2048; p += 512) {       // stage out
    const int z = p >> 4, w = (p & 15) << 1;
    *(float4*)&Z[base0 + (size_t)z * V + w] = *(const float4*)&T[z * PH3 + w];
  }
  for (int p = tid; p < 2048; p += 512) {
    const int z = p >> 4, w = (p & 15) << 1;
    *(float4*)&Z[base1 + (size_t)z * V + w] =
        *(const float4*)&T[SLICE + z * PH3 + w];
  }
}

// K3: per (b, z1), 1024 thr, full-plane LDS, one c[16] per pass.
// Pass 1: column x = group; y-IFFT128 from y-contiguous Z; transposed write.
// Pass 2: row y = group; x-IFFT128; real*sc repacked in-row as f32;
// cooperative 512-B full-line stores to out(b, z1, y, x).
__global__ __launch_bounds__(1024) void k_inv_xy(const float2* __restrict__ Z,
                                                 float* __restrict__ out) {
  __shared__ float2 s[V * PR3];   // 137216 B -> 1 block/CU
  const int tid = threadIdx.x, lane = tid & 63, wave = tid >> 6;
  const int g = tid >> 3, lq = tid & 7;       // g = 0..127
  const int b = blockIdx.x >> 7, z1 = blockIdx.x & 127;
  WFT F;
  F.init(lq);
  const int e = F.e;
  float2 c[16];
  {                                            // pass 1: column x = g
    const size_t zb = ((size_t)(b * V + g) * V + z1) * V;
#pragma unroll
    for (int j = 0; j < 16; ++j) c[j] = Z[zb + e + 8 * j];
    F.inv128(c);
#pragma unroll
    for (int j = 0; j < 16; ++j) s[(e + 8 * j) * PR3 + g] = c[j];
  }
  __syncthreads();
  const float sc = 1.0f / 2097152.0f;          // 1/V^3
  {                                            // pass 2: row y = g
#pragma unroll
    for (int j = 0; j < 16; ++j) c[j] = s[g * PR3 + e + 8 * j];
    F.inv128(c);
    float* fr = (float*)(s + g * PR3);         // in-row f32 repack (safe:
#pragma unroll                                 // wave-ordered read-then-write,
    for (int j = 0; j < 16; ++j)               // row g owned by group g only)
      fr[e + 8 * j] = c[j].x * sc;
  }
  __syncthreads();
  for (int r = wave; r < 128; r += 16) {       // 512-B full-line store per wave
    const size_t gg = (size_t)b * V3 + (size_t)z1 * V2 + (size_t)r * V;
    *(float2*)&out[gg + 2 * lane] =
        *(const float2*)((const float*)(s + r * PR3) + 2 * lane);
  }
}

extern "C" void kernel_launch(void* const* d_in, const int* in_sizes, int n_in,
                              void* d_out, int out_size, void* d_ws, size_t ws_size,
                              hipStream_t stream) {
  const float* v1 = (const float*)d_in[0];
  const float* v2 = (const float*)d_in[1];
  float* out = (float*)d_out;
  float2* Z  = (float2*)d_ws;  // NB*V3*8 = 128 MiB

  k_fwd_xy<<<NB * V * 2, 512, 0, stream>>>(v1, v2, Z);
  k_z_fused<<<NB * 256, 512, 0, stream>>>(Z);   // 2 quarter-slices per block
  k_inv_xy<<<NB * V, 1024, 0, stream>>>(Z, out);
}